// Round 8
// baseline (848.445 us; speedup 1.0000x reference)
//
#include <hip/hip_runtime.h>
#include <hip/hip_cooperative_groups.h>

namespace cg = cooperative_groups;

#define NCLS 8
#define NPT  2048
#define DIM  64
#define FINF 3.402823466e38f
#define INFK 0xFFFFFFFFu
#define INF64 0xFFFFFFFFFFFFFFFFull

typedef unsigned int u32;
typedef unsigned long long u64;
typedef unsigned short u16;
typedef _Float16 f16_t;
typedef __attribute__((ext_vector_type(8))) f16_t f16x8;
typedef __attribute__((ext_vector_type(4))) float f32x4;
typedef __attribute__((ext_vector_type(4))) u32 u32x4;

#define MFMAH(a, b, c) __builtin_amdgcn_mfma_f32_16x16x32_f16((a), (b), (c), 0, 0, 0)

#define ALOAD_U64(p) __hip_atomic_load((p), __ATOMIC_RELAXED, __HIP_MEMORY_SCOPE_AGENT)
#define ALOAD_U32(p) __hip_atomic_load((p), __ATOMIC_RELAXED, __HIP_MEMORY_SCOPE_AGENT)
#define ALOAD_F32(p) __hip_atomic_load((p), __ATOMIC_RELAXED, __HIP_MEMORY_SCOPE_AGENT)
#define ASTORE_U32(p, v) __hip_atomic_store((p), (v), __ATOMIC_RELAXED, __HIP_MEMORY_SCOPE_AGENT)

// ===========================================================================
// Persistent cooperative kernel: entire Boruvka MST loss in ONE dispatch.
// Grid (4,16,NCLS) = 512 blocks x 256 thr; LDS 26.6 KB -> >=2 blocks/CU.
// comp lives ONLY in LDS (redundant identical merge per block -> one grid
// sync per round). minEdge double-buffered with DECREASING round tags in the
// key MSBs instead of resets (stale entries lose atomicMin + tag-filtered).
// All cross-block global reads use agent-scope atomic loads (stale-L1 safe;
// done[] reads MUST be coherent or the break diverges -> deadlock).
// ===========================================================================
__global__ __launch_bounds__(256) void fused2_kernel(
    const float* __restrict__ x, u16* __restrict__ xh, float* __restrict__ sq,
    u64* __restrict__ minEdge /*2*NCLS*NPT*/, float* __restrict__ lossAcc,
    u32* __restrict__ doneG, float* __restrict__ out)
{
    cg::grid_group grid = cg::this_grid();

    __shared__ u16   compL[NPT];                        // 4 KB persistent
    __shared__ float sqC[512];                          // 2 KB persistent
    __shared__ __align__(16) char uni[NPT * 8 + NPT * 2]; // 20 KB union
    __shared__ float rwS[4];
    __shared__ u32   rcS[4];
    __shared__ u32   shRoot, shConv, shDone;

    u64* minT    = (u64*)uni;              // scan:  per-component table
    u64* edgeL   = (u64*)uni;              // merge: edge copy (same region)
    u16* parentL = (u16*)(uni + NPT * 8);  // merge: hook forest

    const int c    = blockIdx.z;
    const int rb   = blockIdx.y;      // row block (128 rows)
    const int cs   = blockIdx.x;      // col split (512 cols)
    const int tid  = threadIdx.x;
    const int lane = tid & 63;
    const int w    = tid >> 6;
    const int b    = (c * 16 + rb) * 4 + cs;

    // ---- phase 0: fp16 convert + row norms + global init ----
    {
        #pragma unroll
        for (int rr = 0; rr < 8; ++rr) {
            int row = b * 32 + w * 8 + rr;
            size_t idx = (size_t)row * DIM + lane;
            float v = x[idx];
            xh[idx] = __builtin_bit_cast(u16, (f16_t)v);   // RNE
            float s = v * v;
            #pragma unroll
            for (int m = 32; m >= 1; m >>= 1) s += __shfl_xor(s, m);
            if (lane == 0) sq[row] = s;
        }
        if (tid < 64) minEdge[(size_t)b * 64 + tid] = INF64;  // both buffers
        if (b == 0 && tid < NCLS) ASTORE_U32(&doneG[tid], 0u);
    }
    __threadfence();
    grid.sync();

    // ---- persistent per-block state ----
    const size_t xbase = (size_t)c * NPT * DIM;
    sqC[tid]       = sq[(size_t)c * NPT + cs * 512 + tid];
    sqC[tid + 256] = sq[(size_t)c * NPT + cs * 512 + 256 + tid];
    #pragma unroll
    for (int k = 0; k < 8; ++k) compL[k * 256 + tid] = (u16)(k * 256 + tid);

    const int kq   = (lane >> 4) * 8;
    const int arow = rb * 128 + w * 32 + (lane & 15);
    f16x8 Ah[2][2];
    #pragma unroll
    for (int rt = 0; rt < 2; ++rt)
        #pragma unroll
        for (int kk = 0; kk < 2; ++kk) {
            size_t off = xbase + (size_t)(arow + rt * 16) * DIM + kk * 32 + kq;
            Ah[rt][kk] = __builtin_bit_cast(f16x8, *(const u32x4*)(xh + off));
        }
    int   rowg_[2][4];
    float sqrow[2][4];
    #pragma unroll
    for (int rt = 0; rt < 2; ++rt)
        #pragma unroll
        for (int r = 0; r < 4; ++r) {
            int rg = rb * 128 + w * 32 + rt * 16 + ((lane >> 4) << 2) + r;
            rowg_[rt][r] = rg;
            sqrow[rt][r] = sq[(size_t)c * NPT + rg];
        }

    bool  mydone    = false;
    float classLoss = 0.0f;
    __syncthreads();

    // ---- Boruvka rounds: one grid sync per round ----
    for (int rnd = 0; rnd < 11; ++rnd) {
        u64* edgeGb = minEdge + ((size_t)(rnd & 1) * NCLS + c) * NPT;

        if (!mydone) {
            // --- scan ---
            #pragma unroll
            for (int k = 0; k < 8; ++k) minT[k * 256 + tid] = INF64;
            __syncthreads();

            u32 crow[2][4];
            #pragma unroll
            for (int rt = 0; rt < 2; ++rt)
                #pragma unroll
                for (int r = 0; r < 4; ++r) crow[rt][r] = compL[rowg_[rt][r]];

            u32 rm[2][4];
            #pragma unroll
            for (int rt = 0; rt < 2; ++rt)
                #pragma unroll
                for (int r = 0; r < 4; ++r) rm[rt][r] = INFK;

            #pragma unroll 2
            for (int ct = 0; ct < 32; ++ct) {
                const int colb = cs * 512 + ct * 16 + (lane & 15);
                f16x8 Bh[2];
                #pragma unroll
                for (int kk = 0; kk < 2; ++kk) {
                    size_t off = xbase + (size_t)colb * DIM + kk * 32 + kq;
                    Bh[kk] = __builtin_bit_cast(f16x8, *(const u32x4*)(xh + off));
                }
                u32   ccol = compL[colb];
                float sqc_ = sqC[ct * 16 + (lane & 15)];

                #pragma unroll
                for (int rt = 0; rt < 2; ++rt) {
                    f32x4 acc = {0.f, 0.f, 0.f, 0.f};
                    acc = MFMAH(Ah[rt][0], Bh[0], acc);
                    acc = MFMAH(Ah[rt][1], Bh[1], acc);
                    #pragma unroll
                    for (int r = 0; r < 4; ++r) {
                        float d2 = fmaf(-2.0f, acc[r], sqrow[rt][r] + sqc_);
                        d2 = fmaxf(d2, 0.0f);
                        u32 bk = (__float_as_uint(d2) + 0x400u) & 0xFFFFF800u;
                        u32 k2 = bk | (u32)colb;
                        k2 = (crow[rt][r] == ccol) ? INFK : k2;   // masks self
                        rm[rt][r] = min(rm[rt][r], k2);
                    }
                }
            }

            const u64 tagbits = (u64)(15 - rnd) << 60;
            #pragma unroll
            for (int rt = 0; rt < 2; ++rt)
                #pragma unroll
                for (int r = 0; r < 4; ++r) {
                    u32 bv = rm[rt][r];
                    #pragma unroll
                    for (int m = 8; m >= 1; m >>= 1)
                        bv = min(bv, (u32)__shfl_xor((int)bv, m));
                    if ((lane & 15) == 0 && bv != INFK) {
                        int rowg = rowg_[rt][r];
                        int colg = (int)(bv & 0x7FFu);
                        u32 d21  = bv >> 11;
                        int mn = rowg < colg ? rowg : colg;
                        int mx = rowg < colg ? colg : rowg;
                        u64 key = tagbits | ((u64)d21 << 22) | ((u64)mn << 11) | (u64)mx;
                        atomicMin(&minT[crow[rt][r]], key);
                    }
                }
            __syncthreads();

            #pragma unroll
            for (int k = 0; k < 8; ++k) {
                int i = k * 256 + tid;
                u64 e = minT[i];
                if (e != INF64) atomicMin(&edgeGb[i], e);
            }
        }
        __threadfence();
        grid.sync();

        // --- uniform break check (done[] as of writes before this sync) ---
        if (tid == 0) {
            u32 alld = 1;
            #pragma unroll
            for (int cc = 0; cc < NCLS; ++cc) alld &= (ALOAD_U32(&doneG[cc]) != 0u);
            shDone = alld;
        }
        __syncthreads();
        if (shDone) break;

        if (!mydone) {
            // --- merge (redundant, identical in all 64 blocks of class c) ---
            #pragma unroll
            for (int k = 0; k < 8; ++k) {
                int i = k * 256 + tid;
                edgeL[i]   = ALOAD_U64(&edgeGb[i]);
                parentL[i] = (u16)i;
            }
            __syncthreads();

            const u64 T = (u64)(15 - rnd);
            float myw = 0.0f;
            u32   mycnt = 0;
            #pragma unroll
            for (int k = 0; k < 8; ++k) {
                int L = k * 256 + tid;
                u64 e = edgeL[L];
                if (e != INF64 && (e >> 60) == T) {
                    int mn = (int)((e >> 11) & 0x7FF);
                    int mx = (int)(e & 0x7FF);
                    u32 A = compL[mn], B = compL[mx];
                    u32 O = (A == (u32)L) ? B : A;
                    bool mutual = (edgeL[O] == e);
                    if (!(mutual && (u32)L > O)) {
                        parentL[L] = (u16)O;
                        float d2 = __uint_as_float(((u32)(e >> 22) & 0x1FFFFFu) << 11);
                        myw += fabsf(sqrtf(d2) - 1.0f);
                        ++mycnt;
                    }
                }
            }
            __syncthreads();

            // safety: break any residual 2-cycle
            #pragma unroll
            for (int k = 0; k < 8; ++k) {
                int L = k * 256 + tid;
                u32 p1 = parentL[L];
                if (p1 != (u32)L && parentL[p1] == (u32)L && (u32)L > p1)
                    parentL[L] = (u16)L;
            }
            __syncthreads();

            // pointer jumping: 11 doublings
            for (int it = 0; it < 11; ++it) {
                u16 np[8];
                #pragma unroll
                for (int k = 0; k < 8; ++k) {
                    int L = k * 256 + tid;
                    np[k] = parentL[parentL[L]];
                }
                __syncthreads();
                #pragma unroll
                for (int k = 0; k < 8; ++k) parentL[k * 256 + tid] = np[k];
                __syncthreads();
            }

            // new comp (LDS only) + convergence + loss reduction
            u16 nc[8];
            #pragma unroll
            for (int k = 0; k < 8; ++k) nc[k] = parentL[compL[k * 256 + tid]];
            if (tid == 0) { shRoot = nc[0]; shConv = 1; }
            __syncthreads();
            u32 bad = 0;
            #pragma unroll
            for (int k = 0; k < 8; ++k) {
                compL[k * 256 + tid] = nc[k];
                bad |= (u32)(nc[k] != (u16)shRoot);
            }
            if (bad) shConv = 0;   // benign race: all writers write 0

            #pragma unroll
            for (int m = 32; m >= 1; m >>= 1) {
                myw   += __shfl_xor(myw, m);
                mycnt += (u32)__shfl_xor((int)mycnt, m);
            }
            if (lane == 0) { rwS[w] = myw; rcS[w] = mycnt; }
            __syncthreads();

            float rwTot = rwS[0] + rwS[1] + rwS[2] + rwS[3];
            u32   rcTot = rcS[0] + rcS[1] + rcS[2] + rcS[3];
            classLoss += rwTot;
            if (shConv != 0u || rcTot == 0u) {
                mydone = true;
                if (rb == 0 && cs == 0 && tid == 0) ASTORE_U32(&doneG[c], 1u);
            }
        }
        __threadfence();
    }

    if (rb == 0 && cs == 0 && tid == 0) lossAcc[c] = classLoss;
    __threadfence();
    grid.sync();
    if (b == 0 && tid == 0) {
        float s = 0.0f;
        for (int cc = 0; cc < NCLS; ++cc) s += ALOAD_F32(&lossAcc[cc]);
        out[0] = s * (1.0f / (float)(NPT - 1));
    }
}

// ===========================================================================
// Fallback path: proven round-7 multi-kernel pipeline (142 us).
// ===========================================================================
__global__ void convinit_kernel(const float* __restrict__ x, u16* __restrict__ xh,
                                float* __restrict__ sq, u32* __restrict__ comp,
                                u64* __restrict__ minEdge, float* __restrict__ lossAcc,
                                u32* __restrict__ done) {
    int row  = blockIdx.x * 4 + (threadIdx.x >> 6);
    int lane = threadIdx.x & 63;
    size_t idx = (size_t)row * DIM + lane;
    float v = x[idx];
    xh[idx] = __builtin_bit_cast(u16, (f16_t)v);
    float s = v * v;
    #pragma unroll
    for (int m = 32; m >= 1; m >>= 1) s += __shfl_xor(s, m);
    if (lane == 0) {
        sq[row]      = s;
        comp[row]    = (u32)(row & (NPT - 1));
        minEdge[row] = INF64;
        if (row < NCLS) { lossAcc[row] = 0.0f; done[row] = 0u; }
    }
}

__global__ __launch_bounds__(256) void scan2h_kernel(
    const u16* __restrict__ xh, const float* __restrict__ sq,
    const u32* __restrict__ comp, u64* __restrict__ minEdge,
    const u32* __restrict__ classDone)
{
    const int c = blockIdx.z;
    if (classDone[c]) return;
    const int cs   = blockIdx.x;
    const int rb   = blockIdx.y;
    const int tid  = threadIdx.x;
    const int lane = tid & 63;
    const int w    = tid >> 6;

    __shared__ u32   compL[NPT];
    __shared__ float sqL[NPT];
    __shared__ u64   minT[NPT];

    const u32*   compG = comp + (size_t)c * NPT;
    const float* sqG   = sq + (size_t)c * NPT;
    #pragma unroll
    for (int k = 0; k < NPT / 256; ++k) {
        int i = k * 256 + tid;
        compL[i] = compG[i];
        sqL[i]   = sqG[i];
        minT[i]  = INF64;
    }
    __syncthreads();

    const size_t xbase = (size_t)c * NPT * DIM;
    const int    kq    = (lane >> 4) * 8;
    const int    arow  = rb * 128 + w * 32 + (lane & 15);

    f16x8 Ah[2][2];
    #pragma unroll
    for (int rt = 0; rt < 2; ++rt)
        #pragma unroll
        for (int kk = 0; kk < 2; ++kk) {
            size_t off = xbase + (size_t)(arow + rt * 16) * DIM + kk * 32 + kq;
            Ah[rt][kk] = __builtin_bit_cast(f16x8, *(const u32x4*)(xh + off));
        }

    int   rowg_[2][4];
    float sqrow[2][4];
    u32   crow[2][4];
    #pragma unroll
    for (int rt = 0; rt < 2; ++rt)
        #pragma unroll
        for (int r = 0; r < 4; ++r) {
            int rg = rb * 128 + w * 32 + rt * 16 + ((lane >> 4) << 2) + r;
            rowg_[rt][r] = rg;
            sqrow[rt][r] = sqL[rg];
            crow[rt][r]  = compL[rg];
        }

    u32 rm[2][4];
    #pragma unroll
    for (int rt = 0; rt < 2; ++rt)
        #pragma unroll
        for (int r = 0; r < 4; ++r) rm[rt][r] = INFK;

    #pragma unroll 2
    for (int ct = 0; ct < 32; ++ct) {
        const int colb = cs * 512 + ct * 16 + (lane & 15);
        f16x8 Bh[2];
        #pragma unroll
        for (int kk = 0; kk < 2; ++kk) {
            size_t off = xbase + (size_t)colb * DIM + kk * 32 + kq;
            Bh[kk] = __builtin_bit_cast(f16x8, *(const u32x4*)(xh + off));
        }
        u32   ccol = compL[colb];
        float sqc_ = sqL[colb];

        #pragma unroll
        for (int rt = 0; rt < 2; ++rt) {
            f32x4 acc = {0.f, 0.f, 0.f, 0.f};
            acc = MFMAH(Ah[rt][0], Bh[0], acc);
            acc = MFMAH(Ah[rt][1], Bh[1], acc);
            #pragma unroll
            for (int r = 0; r < 4; ++r) {
                float d2 = fmaf(-2.0f, acc[r], sqrow[rt][r] + sqc_);
                d2 = fmaxf(d2, 0.0f);
                u32 bk = (__float_as_uint(d2) + 0x400u) & 0xFFFFF800u;
                u32 k2 = bk | (u32)colb;
                k2 = (crow[rt][r] == ccol) ? INFK : k2;
                rm[rt][r] = min(rm[rt][r], k2);
            }
        }
    }

    #pragma unroll
    for (int rt = 0; rt < 2; ++rt)
        #pragma unroll
        for (int r = 0; r < 4; ++r) {
            u32 bv = rm[rt][r];
            #pragma unroll
            for (int m = 8; m >= 1; m >>= 1)
                bv = min(bv, (u32)__shfl_xor((int)bv, m));
            if ((lane & 15) == 0 && bv != INFK) {
                int rowg = rowg_[rt][r];
                int colg = (int)(bv & 0x7FFu);
                u32 d21  = bv >> 11;
                int mn = rowg < colg ? rowg : colg;
                int mx = rowg < colg ? colg : rowg;
                u64 key = ((u64)d21 << 22) | ((u64)mn << 11) | (u64)mx;
                atomicMin(&minT[crow[rt][r]], key);
            }
        }
    __syncthreads();

    u64* edgeG = minEdge + (size_t)c * NPT;
    #pragma unroll
    for (int k = 0; k < NPT / 256; ++k) {
        int i = k * 256 + tid;
        u64 e = minT[i];
        if (e != INF64) atomicMin(&edgeG[i], e);
    }
}

__global__ __launch_bounds__(256) void merge_kernel(u32* __restrict__ comp,
                                                    u64* __restrict__ minEdge,
                                                    float* __restrict__ lossAcc,
                                                    u32* __restrict__ classDone) {
    __shared__ u32   compL[NPT];
    __shared__ u32   parentL[NPT];
    __shared__ u64   edgeL[NPT];
    __shared__ float rw[256];
    __shared__ int   rc[256];
    __shared__ int   conv;

    const int c   = blockIdx.x;
    const int tid = threadIdx.x;
    if (classDone[c]) return;

    u32* compG = comp + (size_t)c * NPT;
    u64* edgeG = minEdge + (size_t)c * NPT;

    #pragma unroll
    for (int k = 0; k < NPT / 256; ++k) {
        int i = k * 256 + tid;
        compL[i]   = compG[i];
        parentL[i] = (u32)i;
        edgeL[i]   = edgeG[i];
    }
    if (tid == 0) conv = 1;
    __syncthreads();

    float myw = 0.0f;
    int   mycnt = 0;
    #pragma unroll
    for (int k = 0; k < NPT / 256; ++k) {
        int L = k * 256 + tid;
        u64 e = edgeL[L];
        if (e != INF64) {
            int mn = (int)((e >> 11) & 0x7FF);
            int mx = (int)(e & 0x7FF);
            u32 A = compL[mn], B = compL[mx];
            u32 O = (A == (u32)L) ? B : A;
            bool mutual = (edgeL[O] == e);
            if (!(mutual && (u32)L > O)) {
                parentL[L] = O;
                float d2 = __uint_as_float((u32)(e >> 22) << 11);
                myw += fabsf(sqrtf(d2) - 1.0f);
                mycnt += 1;
            }
        }
    }
    __syncthreads();

    #pragma unroll
    for (int k = 0; k < NPT / 256; ++k) {
        int L = k * 256 + tid;
        u32 p1 = parentL[L];
        if (p1 != (u32)L && parentL[p1] == (u32)L && (u32)L > p1) parentL[L] = (u32)L;
    }
    __syncthreads();

    for (int it = 0; it < 11; ++it) {
        u32 np[NPT / 256];
        #pragma unroll
        for (int k = 0; k < NPT / 256; ++k) {
            int L = k * 256 + tid;
            np[k] = parentL[parentL[L]];
        }
        __syncthreads();
        #pragma unroll
        for (int k = 0; k < NPT / 256; ++k) parentL[k * 256 + tid] = np[k];
        __syncthreads();
    }

    u32 root0 = parentL[compL[0]];
    #pragma unroll
    for (int k = 0; k < NPT / 256; ++k) {
        int v = k * 256 + tid;
        u32 nc = parentL[compL[v]];
        compG[v] = nc;
        if (nc != root0) conv = 0;
        edgeG[v] = INF64;
    }

    rw[tid] = myw; rc[tid] = mycnt;
    __syncthreads();
    for (int s = 128; s >= 1; s >>= 1) {
        if (tid < s) { rw[tid] += rw[tid + s]; rc[tid] += rc[tid + s]; }
        __syncthreads();
    }
    if (tid == 0) {
        lossAcc[c] += rw[0];
        if (conv || rc[0] == 0) classDone[c] = 1;
    }
}

__global__ void final2_kernel(const float* __restrict__ lossAcc, float* __restrict__ out) {
    if (threadIdx.x == 0 && blockIdx.x == 0) {
        float s = 0.0f;
        for (int cc = 0; cc < NCLS; ++cc) s += lossAcc[cc] * (1.0f / (float)(NPT - 1));
        out[0] = s;
    }
}

extern "C" void kernel_launch(void* const* d_in, const int* in_sizes, int n_in,
                              void* d_out, int out_size, void* d_ws, size_t ws_size,
                              hipStream_t stream) {
    const float* x   = (const float*)d_in[0];
    float*       out = (float*)d_out;

    const size_t nv = (size_t)NCLS * NPT;
    const size_t nx = (size_t)NCLS * NPT * DIM;

    const size_t off_me   = 0;                                  // 2 bufs, u64
    const size_t off_sq   = off_me + 2 * nv * sizeof(u64);
    const size_t off_comp = off_sq + nv * sizeof(float);
    const size_t off_loss = off_comp + nv * sizeof(u32);
    const size_t off_done = off_loss + NCLS * sizeof(float);
    const size_t off_xh   = off_done + NCLS * sizeof(u32);      // 16B-aligned
    const size_t need     = off_xh + nx * sizeof(u16);

    if (ws_size < need) return;   // ws is known-large in this harness

    u64*   minEdge = (u64*)((char*)d_ws + off_me);
    float* sq      = (float*)((char*)d_ws + off_sq);
    u32*   comp    = (u32*)((char*)d_ws + off_comp);
    float* lossAcc = (float*)((char*)d_ws + off_loss);
    u32*   done    = (u32*)((char*)d_ws + off_done);
    u16*   xh      = (u16*)((char*)d_ws + off_xh);

    // Host-side (capture-safe, deterministic) co-residency check for the
    // cooperative launch — round-6 lesson: never coop-launch blind.
    int dev = 0, cus = 0, maxBlk = 0;
    bool coopOK = (hipGetDevice(&dev) == hipSuccess) &&
                  (hipDeviceGetAttribute(&cus, hipDeviceAttributeMultiprocessorCount,
                                         dev) == hipSuccess) &&
                  (hipOccupancyMaxActiveBlocksPerMultiprocessor(
                       &maxBlk, fused2_kernel, 256, 0) == hipSuccess) &&
                  ((long long)maxBlk * cus >= 4LL * 16 * NCLS);

    if (coopOK) {
        void* args[] = {(void*)&x, (void*)&xh, (void*)&sq, (void*)&minEdge,
                        (void*)&lossAcc, (void*)&done, (void*)&out};
        hipLaunchCooperativeKernel(reinterpret_cast<void*>(fused2_kernel),
                                   dim3(4, 16, NCLS), dim3(256), args, 0, stream);
    } else {
        convinit_kernel<<<(NCLS * NPT) / 4, 256, 0, stream>>>(x, xh, sq, comp,
                                                              minEdge, lossAcc, done);
        for (int r = 0; r < 11; ++r) {
            scan2h_kernel<<<dim3(4, NPT / 128, NCLS), 256, 0, stream>>>(
                xh, sq, comp, minEdge, done);
            merge_kernel<<<NCLS, 256, 0, stream>>>(comp, minEdge, lossAcc, done);
        }
        final2_kernel<<<1, 64, 0, stream>>>(lossAcc, out);
    }
}

// Round 9
// 237.650 us; speedup vs baseline: 3.5701x; 3.5701x over previous
//
#include <hip/hip_runtime.h>

#define NCLS 8
#define NPT  2048
#define DIM  64
#define NROUNDS 11
#define FINF 3.402823466e38f
#define INFK 0xFFFFFFFFu
#define INF64 0xFFFFFFFFFFFFFFFFull

typedef unsigned int u32;
typedef unsigned long long u64;
typedef unsigned short u16;
typedef _Float16 f16_t;
typedef __attribute__((ext_vector_type(8))) f16_t f16x8;
typedef __attribute__((ext_vector_type(4))) float f32x4;
typedef __attribute__((ext_vector_type(4))) u32 u32x4;

#define MFMAH(a, b, c) __builtin_amdgcn_mfma_f32_16x16x32_f16((a), (b), (c), 0, 0, 0)
#define ALOAD_U64(p) __hip_atomic_load((p), __ATOMIC_RELAXED, __HIP_MEMORY_SCOPE_AGENT)

// ---------------------------------------------------------------------------
// Kernel 1: fp32 -> fp16 convert + exact fp32 row norms + state init.
// ---------------------------------------------------------------------------
__global__ void convinit_kernel(const float* __restrict__ x, u16* __restrict__ xh,
                                float* __restrict__ sq, u32* __restrict__ comp,
                                u64* __restrict__ minEdge, float* __restrict__ lossAcc,
                                u32* __restrict__ done, u32* __restrict__ counters) {
    int row  = blockIdx.x * 4 + (threadIdx.x >> 6);
    int lane = threadIdx.x & 63;
    size_t idx = (size_t)row * DIM + lane;
    float v = x[idx];
    xh[idx] = __builtin_bit_cast(u16, (f16_t)v);   // RNE
    float s = v * v;
    #pragma unroll
    for (int m = 32; m >= 1; m >>= 1) s += __shfl_xor(s, m);
    if (lane == 0) {
        sq[row]      = s;
        comp[row]    = (u32)(row & (NPT - 1));
        minEdge[row] = INF64;
        if (row < NCLS) { lossAcc[row] = 0.0f; done[row] = 0u; }
    }
    if (blockIdx.x == 0 && threadIdx.x < NROUNDS * NCLS) counters[threadIdx.x] = 0u;
}

// ---------------------------------------------------------------------------
// Kernel 2: fused Boruvka scan + merge (one dispatch per round).
// Scan: 64 blocks/class (4 col-splits x 16 row-blocks), single-pass fp16
// MFMA Gram (bitwise-symmetric -> exact mutual-edge dedup), LDS per-comp
// pre-reduction, flush to global minEdge.
// Then: per-(round,class) ticket; the LAST block of the class acquires
// (threadfence = L2 invalidate, same semantics grid.sync provided in the
// working round-8 kernel) and runs the merge in-dispatch. Round-8 lesson:
// grid.sync costs ~70us/round on ROCm; dispatch boundaries + scoped tickets
// are the cheap barrier. LDS overlays keep footprint at the proven 34 KB.
// ---------------------------------------------------------------------------
__global__ __launch_bounds__(256) void scanmerge_kernel(
    const u16* __restrict__ xh, const float* __restrict__ sq,
    u32* __restrict__ comp, u64* __restrict__ minEdge,
    float* __restrict__ lossAcc, u32* __restrict__ classDone,
    u32* __restrict__ counters, int rnd)
{
    const int c = blockIdx.z;
    if (classDone[c]) return;
    const int cs   = blockIdx.x;      // col split (512 cols)
    const int rb   = blockIdx.y;      // row block (128 rows)
    const int tid  = threadIdx.x;
    const int lane = tid & 63;
    const int w    = tid >> 6;

    __shared__ u32 compL[NPT];                         // 8 KB (scan+merge)
    __shared__ __align__(16) char bufA[NPT * 4];       // 8 KB: sqL | parentL
    __shared__ __align__(16) char bufB[NPT * 8];       // 16 KB: minT | edgeL
    __shared__ float rw[256];
    __shared__ u32   rc[256];
    __shared__ u32   shTicket;
    __shared__ int   conv;

    float* sqL  = (float*)bufA;
    u64*   minT = (u64*)bufB;

    const u32*   compG = comp + (size_t)c * NPT;
    const float* sqG   = sq + (size_t)c * NPT;
    u64*         edgeG = minEdge + (size_t)c * NPT;

    #pragma unroll
    for (int k = 0; k < NPT / 256; ++k) {
        int i = k * 256 + tid;
        compL[i] = compG[i];
        sqL[i]   = sqG[i];
        minT[i]  = INF64;
    }
    __syncthreads();

    const size_t xbase = (size_t)c * NPT * DIM;
    const int    kq    = (lane >> 4) * 8;
    const int    arow  = rb * 128 + w * 32 + (lane & 15);

    f16x8 Ah[2][2];
    #pragma unroll
    for (int rt = 0; rt < 2; ++rt)
        #pragma unroll
        for (int kk = 0; kk < 2; ++kk) {
            size_t off = xbase + (size_t)(arow + rt * 16) * DIM + kk * 32 + kq;
            Ah[rt][kk] = __builtin_bit_cast(f16x8, *(const u32x4*)(xh + off));
        }

    // per-output-slot row constants (C/D: row=(lane>>4)*4+reg, col=lane&15)
    int   rowg_[2][4];
    float sqrow[2][4];
    u32   crow[2][4];
    #pragma unroll
    for (int rt = 0; rt < 2; ++rt)
        #pragma unroll
        for (int r = 0; r < 4; ++r) {
            int rg = rb * 128 + w * 32 + rt * 16 + ((lane >> 4) << 2) + r;
            rowg_[rt][r] = rg;
            sqrow[rt][r] = sqL[rg];
            crow[rt][r]  = compL[rg];
        }

    u32 rm[2][4];
    #pragma unroll
    for (int rt = 0; rt < 2; ++rt)
        #pragma unroll
        for (int r = 0; r < 4; ++r) rm[rt][r] = INFK;

    #pragma unroll 2
    for (int ct = 0; ct < 32; ++ct) {
        const int colb = cs * 512 + ct * 16 + (lane & 15);
        f16x8 Bh[2];
        #pragma unroll
        for (int kk = 0; kk < 2; ++kk) {
            size_t off = xbase + (size_t)colb * DIM + kk * 32 + kq;
            Bh[kk] = __builtin_bit_cast(f16x8, *(const u32x4*)(xh + off));
        }
        u32   ccol = compL[colb];
        float sqc_ = sqL[colb];

        #pragma unroll
        for (int rt = 0; rt < 2; ++rt) {
            f32x4 acc = {0.f, 0.f, 0.f, 0.f};
            acc = MFMAH(Ah[rt][0], Bh[0], acc);
            acc = MFMAH(Ah[rt][1], Bh[1], acc);
            #pragma unroll
            for (int r = 0; r < 4; ++r) {
                float d2 = fmaf(-2.0f, acc[r], sqrow[rt][r] + sqc_);
                d2 = fmaxf(d2, 0.0f);
                u32 bk = (__float_as_uint(d2) + 0x400u) & 0xFFFFF800u;  // RNE 21-bit
                u32 k2 = bk | (u32)colb;
                k2 = (crow[rt][r] == ccol) ? INFK : k2;   // masks self too
                rm[rt][r] = min(rm[rt][r], k2);
            }
        }
    }

    // reduce row-min across the 16 col-lanes, then LDS per-comp table
    #pragma unroll
    for (int rt = 0; rt < 2; ++rt)
        #pragma unroll
        for (int r = 0; r < 4; ++r) {
            u32 bv = rm[rt][r];
            #pragma unroll
            for (int m = 8; m >= 1; m >>= 1)
                bv = min(bv, (u32)__shfl_xor((int)bv, m));
            if ((lane & 15) == 0 && bv != INFK) {
                int rowg = rowg_[rt][r];
                int colg = (int)(bv & 0x7FFu);
                u32 d21  = bv >> 11;
                int mn = rowg < colg ? rowg : colg;
                int mx = rowg < colg ? colg : rowg;
                u64 key = ((u64)d21 << 22) | ((u64)mn << 11) | (u64)mx;
                atomicMin(&minT[crow[rt][r]], key);
            }
        }
    __syncthreads();

    // flush: one global atomic per distinct component present in this block
    #pragma unroll
    for (int k = 0; k < NPT / 256; ++k) {
        int i = k * 256 + tid;
        u64 e = minT[i];
        if (e != INF64) atomicMin(&edgeG[i], e);
    }

    // ---- ticket: last block of (rnd, c) does the merge in-dispatch ----
    __threadfence();                        // release our flushes
    if (tid == 0) shTicket = atomicAdd(&counters[rnd * NCLS + c], 1u);
    __syncthreads();
    if (shTicket != 63u) return;
    __threadfence();                        // acquire: invalidate stale L2

    // ---- merge (this block only; compL still holds comp of class c) ----
    u32* parentL = (u32*)bufA;              // overlays sqL (dead now)
    u64* edgeL   = (u64*)bufB;              // overlays minT
    u32* compGm  = comp + (size_t)c * NPT;

    #pragma unroll
    for (int k = 0; k < NPT / 256; ++k) {
        int i = k * 256 + tid;
        edgeL[i]   = ALOAD_U64(&edgeG[i]);
        parentL[i] = (u32)i;
    }
    if (tid == 0) conv = 1;
    __syncthreads();

    float myw = 0.0f;
    int   mycnt = 0;
    #pragma unroll
    for (int k = 0; k < NPT / 256; ++k) {
        int L = k * 256 + tid;
        u64 e = edgeL[L];
        if (e != INF64) {
            int mn = (int)((e >> 11) & 0x7FF);
            int mx = (int)(e & 0x7FF);
            u32 A = compL[mn], B = compL[mx];
            u32 O = (A == (u32)L) ? B : A;
            bool mutual = (edgeL[O] == e);
            if (!(mutual && (u32)L > O)) {
                parentL[L] = O;
                float d2 = __uint_as_float((u32)(e >> 22) << 11);
                myw += fabsf(sqrtf(d2) - 1.0f);
                mycnt += 1;
            }
        }
    }
    __syncthreads();

    // safety: break any residual 2-cycle (larger id resets to self)
    #pragma unroll
    for (int k = 0; k < NPT / 256; ++k) {
        int L = k * 256 + tid;
        u32 p1 = parentL[L];
        if (p1 != (u32)L && parentL[p1] == (u32)L && (u32)L > p1) parentL[L] = (u32)L;
    }
    __syncthreads();

    // pointer jumping: 11 doublings cover chains up to length 2048
    for (int it = 0; it < 11; ++it) {
        u32 np[NPT / 256];
        #pragma unroll
        for (int k = 0; k < NPT / 256; ++k) {
            int L = k * 256 + tid;
            np[k] = parentL[parentL[L]];
        }
        __syncthreads();
        #pragma unroll
        for (int k = 0; k < NPT / 256; ++k) parentL[k * 256 + tid] = np[k];
        __syncthreads();
    }

    u32 root0 = parentL[compL[0]];
    #pragma unroll
    for (int k = 0; k < NPT / 256; ++k) {
        int v = k * 256 + tid;
        u32 nc = parentL[compL[v]];
        compGm[v] = nc;
        if (nc != root0) conv = 0;     // benign race: all writers write 0
        edgeG[v] = INF64;              // reset for next round
    }

    rw[tid] = myw; rc[tid] = (u32)mycnt;
    __syncthreads();
    for (int s = 128; s >= 1; s >>= 1) {
        if (tid < s) { rw[tid] += rw[tid + s]; rc[tid] += rc[tid + s]; }
        __syncthreads();
    }
    if (tid == 0) {
        lossAcc[c] += rw[0];
        if (conv || rc[0] == 0u) classDone[c] = 1u;
    }
}

// ---------------------------------------------------------------------------
// Finalize: out = sum_c lossAcc[c] / (NPT-1).
// ---------------------------------------------------------------------------
__global__ void final2_kernel(const float* __restrict__ lossAcc, float* __restrict__ out) {
    if (threadIdx.x == 0 && blockIdx.x == 0) {
        float s = 0.0f;
        for (int cc = 0; cc < NCLS; ++cc) s += lossAcc[cc] * (1.0f / (float)(NPT - 1));
        out[0] = s;
    }
}

// ---------------------------------------------------------------------------
// Fallback (ws too small): on-the-fly Prim, 1024 threads/class.
// ---------------------------------------------------------------------------
__global__ __launch_bounds__(1024) void prim_onfly_kernel(const float* __restrict__ x,
                                                          float* __restrict__ loss_out) {
    __shared__ float  redV[2][16];
    __shared__ int    redI[2][16];
    __shared__ float  finV[2];
    __shared__ int    finI[2];
    __shared__ float4 xjs[2][16];

    const int c    = blockIdx.x;
    const int tid  = threadIdx.x;
    const int lane = tid & 63;
    const int wid  = tid >> 6;
    const int v0   = tid * 2;
    const int v1   = tid * 2 + 1;

    float m0 = FINF, m1 = FINF;
    bool  t0 = (v0 == 0);
    bool  t1 = false;

    int   j = 0;
    int   p = 0;
    float loss = 0.0f;

    const float4* xc4 = (const float4*)(x + (size_t)c * NPT * DIM);

    for (int t = 0; t < NPT - 1; ++t) {
        if (tid < 16) xjs[p][tid] = xc4[(size_t)j * 16 + tid];
        __syncthreads();
        float a0 = 0.0f, a1 = 0.0f;
        #pragma unroll
        for (int k = 0; k < 16; ++k) {
            float4 xj = xjs[p][k];
            float4 q0 = xc4[(size_t)v0 * 16 + k];
            float4 q1 = xc4[(size_t)v1 * 16 + k];
            float dx;
            dx = xj.x - q0.x; a0 = fmaf(dx, dx, a0);
            dx = xj.y - q0.y; a0 = fmaf(dx, dx, a0);
            dx = xj.z - q0.z; a0 = fmaf(dx, dx, a0);
            dx = xj.w - q0.w; a0 = fmaf(dx, dx, a0);
            dx = xj.x - q1.x; a1 = fmaf(dx, dx, a1);
            dx = xj.y - q1.y; a1 = fmaf(dx, dx, a1);
            dx = xj.z - q1.z; a1 = fmaf(dx, dx, a1);
            dx = xj.w - q1.w; a1 = fmaf(dx, dx, a1);
        }
        float d0 = a0 > 0.0f ? sqrtf(a0) : 0.0f;
        float d1 = a1 > 0.0f ? sqrtf(a1) : 0.0f;

        if (!t0) m0 = fminf(m0, d0);
        if (!t1) m1 = fminf(m1, d1);

        float val; int idx;
        if (m0 <= m1) { val = m0; idx = v0; }
        else          { val = m1; idx = v1; }

        #pragma unroll
        for (int m = 32; m >= 1; m >>= 1) {
            float ov = __shfl_xor(val, m);
            int   oi = __shfl_xor(idx, m);
            if (ov < val || (ov == val && oi < idx)) { val = ov; idx = oi; }
        }
        if (lane == 0) { redV[p][wid] = val; redI[p][wid] = idx; }
        __syncthreads();

        if (wid == 0) {
            float v  = (lane < 16) ? redV[p][lane] : FINF;
            int   i2 = (lane < 16) ? redI[p][lane] : 0x7fffffff;
            #pragma unroll
            for (int m = 8; m >= 1; m >>= 1) {
                float ov = __shfl_xor(v, m);
                int   oi = __shfl_xor(i2, m);
                if (ov < v || (ov == v && oi < i2)) { v = ov; i2 = oi; }
            }
            if (lane == 0) { finV[p] = v; finI[p] = i2; }
        }
        __syncthreads();

        float bv = finV[p];
        j        = finI[p];
        if (tid == 0) loss += fabsf(bv - 1.0f);
        if (v0 == j) { t0 = true; m0 = FINF; }
        if (v1 == j) { t1 = true; m1 = FINF; }
        p ^= 1;
    }

    if (tid == 0) loss_out[c] = loss / (float)(NPT - 1);
}

__global__ void finalize_kernel(const float* __restrict__ loss, float* __restrict__ out) {
    if (threadIdx.x == 0 && blockIdx.x == 0) {
        float s = 0.0f;
        for (int c = 0; c < NCLS; ++c) s += loss[c];
        out[0] = s;
    }
}

extern "C" void kernel_launch(void* const* d_in, const int* in_sizes, int n_in,
                              void* d_out, int out_size, void* d_ws, size_t ws_size,
                              hipStream_t stream) {
    const float* x   = (const float*)d_in[0];
    float*       out = (float*)d_out;

    const size_t nv = (size_t)NCLS * NPT;
    const size_t nx = (size_t)NCLS * NPT * DIM;

    const size_t off_me   = 0;                                  // u64, 8-aligned
    const size_t off_sq   = off_me + nv * sizeof(u64);
    const size_t off_comp = off_sq + nv * sizeof(float);
    const size_t off_loss = off_comp + nv * sizeof(u32);
    const size_t off_done = off_loss + NCLS * sizeof(float);
    const size_t off_cnt  = off_done + NCLS * sizeof(u32);
    const size_t off_xh   = off_cnt + NROUNDS * NCLS * sizeof(u32);
    const size_t need     = off_xh + nx * sizeof(u16);

    if (ws_size >= need) {
        u64*   minEdge  = (u64*)((char*)d_ws + off_me);
        float* sq       = (float*)((char*)d_ws + off_sq);
        u32*   comp     = (u32*)((char*)d_ws + off_comp);
        float* lossAcc  = (float*)((char*)d_ws + off_loss);
        u32*   done     = (u32*)((char*)d_ws + off_done);
        u32*   counters = (u32*)((char*)d_ws + off_cnt);
        u16*   xh       = (u16*)((char*)d_ws + off_xh);

        convinit_kernel<<<(NCLS * NPT) / 4, 256, 0, stream>>>(x, xh, sq, comp,
                                                              minEdge, lossAcc, done,
                                                              counters);
        for (int r = 0; r < NROUNDS; ++r) {
            scanmerge_kernel<<<dim3(4, NPT / 128, NCLS), 256, 0, stream>>>(
                xh, sq, comp, minEdge, lossAcc, done, counters, r);
        }
        final2_kernel<<<1, 64, 0, stream>>>(lossAcc, out);
    } else {
        float* loss = (float*)d_ws;
        prim_onfly_kernel<<<NCLS, 1024, 0, stream>>>(x, loss);
        finalize_kernel<<<1, 64, 0, stream>>>(loss, out);
    }
}

// Round 10
// 149.032 us; speedup vs baseline: 5.6930x; 1.5946x over previous
//
#include <hip/hip_runtime.h>

#define NCLS 8
#define NPT  2048
#define DIM  64
#define NROUNDS 11
#define FINF 3.402823466e38f
#define INFK 0xFFFFFFFFu
#define INF64 0xFFFFFFFFFFFFFFFFull

typedef unsigned int u32;
typedef unsigned long long u64;
typedef unsigned short u16;
typedef _Float16 f16_t;
typedef __attribute__((ext_vector_type(8))) f16_t f16x8;
typedef __attribute__((ext_vector_type(4))) float f32x4;
typedef __attribute__((ext_vector_type(4))) u32 u32x4;

#define MFMAH(a, b, c) __builtin_amdgcn_mfma_f32_16x16x32_f16((a), (b), (c), 0, 0, 0)
#define ALOAD_U64(p) __hip_atomic_load((p), __ATOMIC_RELAXED, __HIP_MEMORY_SCOPE_AGENT)

// ---------------------------------------------------------------------------
// Kernel 1: fp32 -> fp16 convert + exact fp32 row norms + state init.
// ---------------------------------------------------------------------------
__global__ void convinit_kernel(const float* __restrict__ x, u16* __restrict__ xh,
                                float* __restrict__ sq, u32* __restrict__ comp,
                                u64* __restrict__ minEdge, float* __restrict__ lossAcc,
                                u32* __restrict__ done, u32* __restrict__ counters) {
    int row  = blockIdx.x * 4 + (threadIdx.x >> 6);
    int lane = threadIdx.x & 63;
    size_t idx = (size_t)row * DIM + lane;
    float v = x[idx];
    xh[idx] = __builtin_bit_cast(u16, (f16_t)v);   // RNE
    float s = v * v;
    #pragma unroll
    for (int m = 32; m >= 1; m >>= 1) s += __shfl_xor(s, m);
    if (lane == 0) {
        sq[row]      = s;
        comp[row]    = (u32)(row & (NPT - 1));
        minEdge[row] = INF64;
        if (row < NCLS) { lossAcc[row] = 0.0f; done[row] = 0u; }
    }
    if (blockIdx.x == 0 && threadIdx.x < NROUNDS * NCLS) counters[threadIdx.x] = 0u;
}

// ---------------------------------------------------------------------------
// Kernel 2: fused Boruvka scan + merge (one dispatch per round), FENCE-FREE.
// Round-9 lesson: per-block __threadfence() on multi-XCD CDNA costs ~60us/
// dispatch (L2 writeback storms) — as expensive as grid.sync. All cross-block
// traffic here is device-scope ATOMICS (coherent-point ops, no cache maint):
//   scan blocks: LDS-pre-reduced winners -> atomicMin(edgeG) ->
//   __syncthreads (drains every wave's vmem: vmcnt(0) before s_barrier) ->
//   relaxed agent fetch_add ticket; last block of the class reads edgeG via
//   agent-scope atomic loads and merges in-dispatch. Plain-store outputs
//   (comp/lossAcc/done/edgeG reset) are read only by the NEXT dispatch.
// ---------------------------------------------------------------------------
__global__ __launch_bounds__(256) void scanmerge_kernel(
    const u16* __restrict__ xh, const float* __restrict__ sq,
    u32* __restrict__ comp, u64* __restrict__ minEdge,
    float* __restrict__ lossAcc, u32* __restrict__ classDone,
    u32* __restrict__ counters, int rnd)
{
    const int c = blockIdx.z;
    if (classDone[c]) return;
    const int cs   = blockIdx.x;      // col split (512 cols)
    const int rb   = blockIdx.y;      // row block (128 rows)
    const int tid  = threadIdx.x;
    const int lane = tid & 63;
    const int w    = tid >> 6;

    __shared__ u32 compL[NPT];                         // 8 KB (scan+merge)
    __shared__ __align__(16) char bufA[NPT * 4];       // 8 KB: sqL | parentL
    __shared__ __align__(16) char bufB[NPT * 8];       // 16 KB: minT | edgeL
    __shared__ float rw[256];
    __shared__ u32   rc[256];
    __shared__ u32   shTicket;
    __shared__ int   conv;

    float* sqL  = (float*)bufA;
    u64*   minT = (u64*)bufB;

    const u32*   compG = comp + (size_t)c * NPT;
    const float* sqG   = sq + (size_t)c * NPT;
    u64*         edgeG = minEdge + (size_t)c * NPT;

    #pragma unroll
    for (int k = 0; k < NPT / 256; ++k) {
        int i = k * 256 + tid;
        compL[i] = compG[i];
        sqL[i]   = sqG[i];
        minT[i]  = INF64;
    }
    __syncthreads();

    const size_t xbase = (size_t)c * NPT * DIM;
    const int    kq    = (lane >> 4) * 8;
    const int    arow  = rb * 128 + w * 32 + (lane & 15);

    f16x8 Ah[2][2];
    #pragma unroll
    for (int rt = 0; rt < 2; ++rt)
        #pragma unroll
        for (int kk = 0; kk < 2; ++kk) {
            size_t off = xbase + (size_t)(arow + rt * 16) * DIM + kk * 32 + kq;
            Ah[rt][kk] = __builtin_bit_cast(f16x8, *(const u32x4*)(xh + off));
        }

    // per-output-slot row constants (C/D: row=(lane>>4)*4+reg, col=lane&15)
    int   rowg_[2][4];
    float sqrow[2][4];
    u32   crow[2][4];
    #pragma unroll
    for (int rt = 0; rt < 2; ++rt)
        #pragma unroll
        for (int r = 0; r < 4; ++r) {
            int rg = rb * 128 + w * 32 + rt * 16 + ((lane >> 4) << 2) + r;
            rowg_[rt][r] = rg;
            sqrow[rt][r] = sqL[rg];
            crow[rt][r]  = compL[rg];
        }

    u32 rm[2][4];
    #pragma unroll
    for (int rt = 0; rt < 2; ++rt)
        #pragma unroll
        for (int r = 0; r < 4; ++r) rm[rt][r] = INFK;

    #pragma unroll 2
    for (int ct = 0; ct < 32; ++ct) {
        const int colb = cs * 512 + ct * 16 + (lane & 15);
        f16x8 Bh[2];
        #pragma unroll
        for (int kk = 0; kk < 2; ++kk) {
            size_t off = xbase + (size_t)colb * DIM + kk * 32 + kq;
            Bh[kk] = __builtin_bit_cast(f16x8, *(const u32x4*)(xh + off));
        }
        u32   ccol = compL[colb];
        float sqc_ = sqL[colb];

        #pragma unroll
        for (int rt = 0; rt < 2; ++rt) {
            f32x4 acc = {0.f, 0.f, 0.f, 0.f};
            acc = MFMAH(Ah[rt][0], Bh[0], acc);
            acc = MFMAH(Ah[rt][1], Bh[1], acc);
            #pragma unroll
            for (int r = 0; r < 4; ++r) {
                float d2 = fmaf(-2.0f, acc[r], sqrow[rt][r] + sqc_);
                d2 = fmaxf(d2, 0.0f);
                u32 bk = (__float_as_uint(d2) + 0x400u) & 0xFFFFF800u;  // RNE 21-bit
                u32 k2 = bk | (u32)colb;
                k2 = (crow[rt][r] == ccol) ? INFK : k2;   // masks self too
                rm[rt][r] = min(rm[rt][r], k2);
            }
        }
    }

    // reduce row-min across the 16 col-lanes, then LDS per-comp table
    #pragma unroll
    for (int rt = 0; rt < 2; ++rt)
        #pragma unroll
        for (int r = 0; r < 4; ++r) {
            u32 bv = rm[rt][r];
            #pragma unroll
            for (int m = 8; m >= 1; m >>= 1)
                bv = min(bv, (u32)__shfl_xor((int)bv, m));
            if ((lane & 15) == 0 && bv != INFK) {
                int rowg = rowg_[rt][r];
                int colg = (int)(bv & 0x7FFu);
                u32 d21  = bv >> 11;
                int mn = rowg < colg ? rowg : colg;
                int mx = rowg < colg ? colg : rowg;
                u64 key = ((u64)d21 << 22) | ((u64)mn << 11) | (u64)mx;
                atomicMin(&minT[crow[rt][r]], key);
            }
        }
    __syncthreads();

    // flush: one global atomic per distinct component present in this block
    #pragma unroll
    for (int k = 0; k < NPT / 256; ++k) {
        int i = k * 256 + tid;
        u64 e = minT[i];
        if (e != INF64) atomicMin(&edgeG[i], e);
    }

    // ---- fence-free ticket: last block of (rnd, c) merges in-dispatch ----
    __syncthreads();   // every wave issues s_waitcnt vmcnt(0) before barrier:
                       // ALL of this block's edgeG atomicMins are complete.
    if (tid == 0)
        shTicket = __hip_atomic_fetch_add(&counters[rnd * NCLS + c], 1u,
                                          __ATOMIC_RELAXED, __HIP_MEMORY_SCOPE_AGENT);
    __syncthreads();   // publish ticket (also a compiler barrier: merge loads
                       // below cannot be hoisted above it)
    if (shTicket != 63u) return;

    // ---- merge (this block only; compL still holds comp of class c) ----
    u32* parentL = (u32*)bufA;              // overlays sqL (dead now)
    u64* edgeL   = (u64*)bufB;              // overlays minT
    u32* compGm  = comp + (size_t)c * NPT;

    #pragma unroll
    for (int k = 0; k < NPT / 256; ++k) {
        int i = k * 256 + tid;
        edgeL[i]   = ALOAD_U64(&edgeG[i]);  // agent-scope: reads coherent point
        parentL[i] = (u32)i;
    }
    if (tid == 0) conv = 1;
    __syncthreads();

    float myw = 0.0f;
    int   mycnt = 0;
    #pragma unroll
    for (int k = 0; k < NPT / 256; ++k) {
        int L = k * 256 + tid;
        u64 e = edgeL[L];
        if (e != INF64) {
            int mn = (int)((e >> 11) & 0x7FF);
            int mx = (int)(e & 0x7FF);
            u32 A = compL[mn], B = compL[mx];
            u32 O = (A == (u32)L) ? B : A;
            bool mutual = (edgeL[O] == e);
            if (!(mutual && (u32)L > O)) {
                parentL[L] = O;
                float d2 = __uint_as_float((u32)(e >> 22) << 11);
                myw += fabsf(sqrtf(d2) - 1.0f);
                mycnt += 1;
            }
        }
    }
    __syncthreads();

    // safety: break any residual 2-cycle (larger id resets to self)
    #pragma unroll
    for (int k = 0; k < NPT / 256; ++k) {
        int L = k * 256 + tid;
        u32 p1 = parentL[L];
        if (p1 != (u32)L && parentL[p1] == (u32)L && (u32)L > p1) parentL[L] = (u32)L;
    }
    __syncthreads();

    // pointer jumping: 11 doublings cover chains up to length 2048
    for (int it = 0; it < 11; ++it) {
        u32 np[NPT / 256];
        #pragma unroll
        for (int k = 0; k < NPT / 256; ++k) {
            int L = k * 256 + tid;
            np[k] = parentL[parentL[L]];
        }
        __syncthreads();
        #pragma unroll
        for (int k = 0; k < NPT / 256; ++k) parentL[k * 256 + tid] = np[k];
        __syncthreads();
    }

    u32 root0 = parentL[compL[0]];
    #pragma unroll
    for (int k = 0; k < NPT / 256; ++k) {
        int v = k * 256 + tid;
        u32 nc = parentL[compL[v]];
        compGm[v] = nc;
        if (nc != root0) conv = 0;     // benign race: all writers write 0
        edgeG[v] = INF64;              // reset for next round
    }

    rw[tid] = myw; rc[tid] = (u32)mycnt;
    __syncthreads();
    for (int s = 128; s >= 1; s >>= 1) {
        if (tid < s) { rw[tid] += rw[tid + s]; rc[tid] += rc[tid + s]; }
        __syncthreads();
    }
    if (tid == 0) {
        lossAcc[c] += rw[0];
        if (conv || rc[0] == 0u) classDone[c] = 1u;
    }
}

// ---------------------------------------------------------------------------
// Finalize: out = sum_c lossAcc[c] / (NPT-1).
// ---------------------------------------------------------------------------
__global__ void final2_kernel(const float* __restrict__ lossAcc, float* __restrict__ out) {
    if (threadIdx.x == 0 && blockIdx.x == 0) {
        float s = 0.0f;
        for (int cc = 0; cc < NCLS; ++cc) s += lossAcc[cc] * (1.0f / (float)(NPT - 1));
        out[0] = s;
    }
}

// ---------------------------------------------------------------------------
// Fallback (ws too small): on-the-fly Prim, 1024 threads/class.
// ---------------------------------------------------------------------------
__global__ __launch_bounds__(1024) void prim_onfly_kernel(const float* __restrict__ x,
                                                          float* __restrict__ loss_out) {
    __shared__ float  redV[2][16];
    __shared__ int    redI[2][16];
    __shared__ float  finV[2];
    __shared__ int    finI[2];
    __shared__ float4 xjs[2][16];

    const int c    = blockIdx.x;
    const int tid  = threadIdx.x;
    const int lane = tid & 63;
    const int wid  = tid >> 6;
    const int v0   = tid * 2;
    const int v1   = tid * 2 + 1;

    float m0 = FINF, m1 = FINF;
    bool  t0 = (v0 == 0);
    bool  t1 = false;

    int   j = 0;
    int   p = 0;
    float loss = 0.0f;

    const float4* xc4 = (const float4*)(x + (size_t)c * NPT * DIM);

    for (int t = 0; t < NPT - 1; ++t) {
        if (tid < 16) xjs[p][tid] = xc4[(size_t)j * 16 + tid];
        __syncthreads();
        float a0 = 0.0f, a1 = 0.0f;
        #pragma unroll
        for (int k = 0; k < 16; ++k) {
            float4 xj = xjs[p][k];
            float4 q0 = xc4[(size_t)v0 * 16 + k];
            float4 q1 = xc4[(size_t)v1 * 16 + k];
            float dx;
            dx = xj.x - q0.x; a0 = fmaf(dx, dx, a0);
            dx = xj.y - q0.y; a0 = fmaf(dx, dx, a0);
            dx = xj.z - q0.z; a0 = fmaf(dx, dx, a0);
            dx = xj.w - q0.w; a0 = fmaf(dx, dx, a0);
            dx = xj.x - q1.x; a1 = fmaf(dx, dx, a1);
            dx = xj.y - q1.y; a1 = fmaf(dx, dx, a1);
            dx = xj.z - q1.z; a1 = fmaf(dx, dx, a1);
            dx = xj.w - q1.w; a1 = fmaf(dx, dx, a1);
        }
        float d0 = a0 > 0.0f ? sqrtf(a0) : 0.0f;
        float d1 = a1 > 0.0f ? sqrtf(a1) : 0.0f;

        if (!t0) m0 = fminf(m0, d0);
        if (!t1) m1 = fminf(m1, d1);

        float val; int idx;
        if (m0 <= m1) { val = m0; idx = v0; }
        else          { val = m1; idx = v1; }

        #pragma unroll
        for (int m = 32; m >= 1; m >>= 1) {
            float ov = __shfl_xor(val, m);
            int   oi = __shfl_xor(idx, m);
            if (ov < val || (ov == val && oi < idx)) { val = ov; idx = oi; }
        }
        if (lane == 0) { redV[p][wid] = val; redI[p][wid] = idx; }
        __syncthreads();

        if (wid == 0) {
            float v  = (lane < 16) ? redV[p][lane] : FINF;
            int   i2 = (lane < 16) ? redI[p][lane] : 0x7fffffff;
            #pragma unroll
            for (int m = 8; m >= 1; m >>= 1) {
                float ov = __shfl_xor(v, m);
                int   oi = __shfl_xor(i2, m);
                if (ov < v || (ov == v && oi < i2)) { v = ov; i2 = oi; }
            }
            if (lane == 0) { finV[p] = v; finI[p] = i2; }
        }
        __syncthreads();

        float bv = finV[p];
        j        = finI[p];
        if (tid == 0) loss += fabsf(bv - 1.0f);
        if (v0 == j) { t0 = true; m0 = FINF; }
        if (v1 == j) { t1 = true; m1 = FINF; }
        p ^= 1;
    }

    if (tid == 0) loss_out[c] = loss / (float)(NPT - 1);
}

__global__ void finalize_kernel(const float* __restrict__ loss, float* __restrict__ out) {
    if (threadIdx.x == 0 && blockIdx.x == 0) {
        float s = 0.0f;
        for (int c = 0; c < NCLS; ++c) s += loss[c];
        out[0] = s;
    }
}

extern "C" void kernel_launch(void* const* d_in, const int* in_sizes, int n_in,
                              void* d_out, int out_size, void* d_ws, size_t ws_size,
                              hipStream_t stream) {
    const float* x   = (const float*)d_in[0];
    float*       out = (float*)d_out;

    const size_t nv = (size_t)NCLS * NPT;
    const size_t nx = (size_t)NCLS * NPT * DIM;

    const size_t off_me   = 0;                                  // u64, 8-aligned
    const size_t off_sq   = off_me + nv * sizeof(u64);
    const size_t off_comp = off_sq + nv * sizeof(float);
    const size_t off_loss = off_comp + nv * sizeof(u32);
    const size_t off_done = off_loss + NCLS * sizeof(float);
    const size_t off_cnt  = off_done + NCLS * sizeof(u32);
    const size_t off_xh   = off_cnt + NROUNDS * NCLS * sizeof(u32);
    const size_t need     = off_xh + nx * sizeof(u16);

    if (ws_size >= need) {
        u64*   minEdge  = (u64*)((char*)d_ws + off_me);
        float* sq       = (float*)((char*)d_ws + off_sq);
        u32*   comp     = (u32*)((char*)d_ws + off_comp);
        float* lossAcc  = (float*)((char*)d_ws + off_loss);
        u32*   done     = (u32*)((char*)d_ws + off_done);
        u32*   counters = (u32*)((char*)d_ws + off_cnt);
        u16*   xh       = (u16*)((char*)d_ws + off_xh);

        convinit_kernel<<<(NCLS * NPT) / 4, 256, 0, stream>>>(x, xh, sq, comp,
                                                              minEdge, lossAcc, done,
                                                              counters);
        for (int r = 0; r < NROUNDS; ++r) {
            scanmerge_kernel<<<dim3(4, NPT / 128, NCLS), 256, 0, stream>>>(
                xh, sq, comp, minEdge, lossAcc, done, counters, r);
        }
        final2_kernel<<<1, 64, 0, stream>>>(lossAcc, out);
    } else {
        float* loss = (float*)d_ws;
        prim_onfly_kernel<<<NCLS, 1024, 0, stream>>>(x, loss);
        finalize_kernel<<<1, 64, 0, stream>>>(loss, out);
    }
}